// Round 2
// baseline (504.310 us; speedup 1.0000x reference)
//
#include <hip/hip_runtime.h>
#include <hip/hip_bf16.h>

namespace {

constexpr int Bn = 2, Sn = 2048, Hn = 16, Dn = 128;
constexpr int QBLK = 128;   // 4 q-waves x 32 queries
constexpr int KVBLK = 32;   // keys per chunk; superstep = 4 chunks (one per key-group)
constexpr int RS = Hn * Dn; // 2048 floats
constexpr float QSCALE = 0.08838834764831845f * 1.4426950408889634f; // 1/sqrt(D)*log2(e)

typedef __bf16 bf16x8 __attribute__((ext_vector_type(8)));
typedef __bf16 bf16x2 __attribute__((ext_vector_type(2)));
typedef float  f32x16 __attribute__((ext_vector_type(16)));

__device__ __forceinline__ f32x16 mfma32(bf16x8 a, bf16x8 b, f32x16 c) {
  return __builtin_amdgcn_mfma_f32_32x32x16_bf16(a, b, c, 0, 0, 0);
}
__device__ __forceinline__ unsigned pack2(float a, float b) {
  union { __bf16 h[2]; unsigned u; } r;
  r.h[0] = (__bf16)a; r.h[1] = (__bf16)b;
  return r.u;
}
__device__ __forceinline__ float pair_max(float x) { return fmaxf(x, __shfl_xor(x, 32)); }
__device__ __forceinline__ float pair_sum(float x) { return x + __shfl_xor(x, 32); }
__device__ __forceinline__ float f4e(const float4& v, int j) {
  return j == 0 ? v.x : j == 1 ? v.y : j == 2 ? v.z : v.w;
}
__device__ __forceinline__ float lane_bcast(int row, float v) {
  return __uint_as_float(__builtin_amdgcn_ds_bpermute(row * 4, __float_as_uint(v)));
}

// lgkm-only barrier: publish LDS, leave register-destined global prefetches in flight.
__device__ __forceinline__ void pipeline_barrier() {
  __builtin_amdgcn_sched_barrier(0);
  asm volatile("s_waitcnt lgkmcnt(0)" ::: "memory");
  __builtin_amdgcn_s_barrier();
  __builtin_amdgcn_sched_barrier(0);
}

// Balanced schedule: 256 blocks (1/CU), 16 waves each (4 key-groups x 4 q-waves).
// Block p processes tiles (15-p) then (p) sequentially: (16-p)+(p+1) = 17
// supersteps for EVERY block -> no solo phase, constant 16-wave occupancy.
// Superstep = 4 chunks of 32 keys (group g takes chunk 4t+g). K/V double-buffered
// (2 x 32 KB each, 128 KB total). Inner per-wave code identical to the verified
// r8 S-pipeline. Epilogue: 4->2->1 merge tree (verified 2-way merge, twice).
__global__ __launch_bounds__(1024, 4)
void fa_fwd(const float* __restrict__ Q, const float* __restrict__ K,
            const float* __restrict__ V, float* __restrict__ O)
{
  __shared__ __align__(16) __bf16 Klds[2][4][KVBLK * 128]; // 64 KB, dbuf by superstep
  __shared__ __align__(16) __bf16 Vt[2][4][128 * KVBLK];   // 64 KB, dbuf by superstep

  const int tid  = threadIdx.x;
  const int lane = tid & 63;
  const int wave = tid >> 6;    // 0..15
  const int col  = lane & 31;
  const int hi   = lane >> 5;
  const int grp  = wave >> 2;   // key-group 0..3: chunk 4t+grp
  const int wq   = wave & 3;    // q-wave within group: rows q0w..q0w+31

  // 4 heads per XCD (same-L2 K/V); 8 tile-pairs per head.
  const int xcd  = (int)blockIdx.x & 7;
  const int s    = (int)blockIdx.x >> 3;    // 0..31
  const int hidx = xcd * 4 + (s & 3);       // 0..31
  const int b    = hidx >> 4, h = hidx & 15;
  const int p    = s >> 2;                  // tile-pair 0..7
  const size_t base = ((size_t)b * Sn) * RS + (size_t)h * Dn;

  // staging: quarter sq (== grp for compute waves) stages chunk 4*ss+sq
  const int sq = tid >> 8, ht = tid & 255;
  const int skey = ht >> 3, sd = (ht & 7) * 16;
  const int vkey = (ht & 15) * 2, vd = (ht >> 4) * 8;

  float4 kr[4], vr[4];
  auto loadK = [&](int ss) {
    const int kv0 = (4 * ss + sq) * KVBLK;
    const float* kp = K + base + (size_t)(kv0 + skey) * RS + sd;
#pragma unroll
    for (int i = 0; i < 4; ++i) kr[i] = *(const float4*)(kp + 4 * i);
  };
  auto loadV = [&](int ss) {
    const int kv0 = (4 * ss + sq) * KVBLK;
    const float* vp = V + base + (size_t)(kv0 + vkey) * RS + vd;
    vr[0] = *(const float4*)(vp);
    vr[1] = *(const float4*)(vp + 4);
    vr[2] = *(const float4*)(vp + RS);
    vr[3] = *(const float4*)(vp + RS + 4);
  };
  auto stageK = [&](int ss) {
    char* kb = (char*)&Klds[ss & 1][sq][0];
    const int kbase = skey * 256 + sd * 2;
    const int kswz  = (skey & 7) << 4;
#pragma unroll
    for (int i = 0; i < 2; ++i) {
      bf16x8 f;
      f[0] = (__bf16)kr[2*i].x;   f[1] = (__bf16)kr[2*i].y;
      f[2] = (__bf16)kr[2*i].z;   f[3] = (__bf16)kr[2*i].w;
      f[4] = (__bf16)kr[2*i+1].x; f[5] = (__bf16)kr[2*i+1].y;
      f[6] = (__bf16)kr[2*i+1].z; f[7] = (__bf16)kr[2*i+1].w;
      *(bf16x8*)(kb + ((kbase + 16 * i) ^ kswz)) = f;
    }
  };
  auto stageV = [&](int ss) {
    char* vb = (char*)&Vt[ss & 1][sq][0];
#pragma unroll
    for (int j = 0; j < 8; ++j) {
      const int d = vd + j;
      bf16x2 w;
      w[0] = (__bf16)f4e(vr[j >> 2], j & 3);
      w[1] = (__bf16)f4e(vr[2 + (j >> 2)], j & 3);
      const int addr = (d * 64 + vkey * 2) ^ ((d & 3) << 4) ^ (((d >> 3) & 1) << 6);
      *(bf16x2*)(vb + addr) = w;
    }
  };

  const int cswz = (col & 7) << 4;
  const int vswz = ((col & 3) << 4) ^ (((col >> 3) & 1) << 6);

#pragma unroll 1
  for (int tp = 0; tp < 2; ++tp) {
    const int qt  = tp ? p : (15 - p);
    const int q0w = qt * QBLK + wq * 32;
    const int T   = qt + 1;              // supersteps of 128 keys

    // ---- Q fragments, scaled ----
    bf16x8 qf[8];
    {
      const float* qp = Q + base + (size_t)(q0w + col) * RS + hi * 8;
#pragma unroll
      for (int kk = 0; kk < 8; ++kk) {
        float4 a = *(const float4*)(qp + kk * 16);
        float4 c2 = *(const float4*)(qp + kk * 16 + 4);
        bf16x8 f;
        f[0] = (__bf16)(a.x * QSCALE);  f[1] = (__bf16)(a.y * QSCALE);
        f[2] = (__bf16)(a.z * QSCALE);  f[3] = (__bf16)(a.w * QSCALE);
        f[4] = (__bf16)(c2.x * QSCALE); f[5] = (__bf16)(c2.y * QSCALE);
        f[6] = (__bf16)(c2.z * QSCALE); f[7] = (__bf16)(c2.w * QSCALE);
        qf[kk] = f;
      }
    }

    f32x16 o0 = {}, o1 = {}, o2 = {}, o3 = {};
    float m = -1e30f, l = 0.f;

    // ---- prologue ----
    loadK(0); loadV(0);
    stageK(0);
    if (1 < T) loadK(1);
    stageV(0);
    if (1 < T) loadV(1);
    if (1 < T) stageK(1);
    if (2 < T) loadK(2);
    pipeline_barrier();              // K0,(K1),V0 published

    // S(0)
    f32x16 st_cur = {};
    if (grp * KVBLK <= q0w + 31) {
      const char* kb = (const char*)&Klds[0][grp][0];
      __builtin_amdgcn_s_setprio(1);
#pragma unroll
      for (int kk = 0; kk < 8; ++kk) {
        bf16x8 ka = *(const bf16x8*)(kb + ((col * 256 + kk * 32 + hi * 16) ^ cswz));
        st_cur = mfma32(ka, qf[kk], st_cur);
      }
      __builtin_amdgcn_s_setprio(0);
    }
    pipeline_barrier();              // fence Klds[0] reads vs iter-0 stageK(2)

#pragma unroll 1
    for (int t = 0; t < T; ++t) {
      // ---- QK^T(t+1) on MFMA pipe; softmax(t)+PV(t) overlap on VALU ----
      f32x16 stn = {};
      const int icn = 4 * (t + 1) + grp;
      if (t + 1 < T && icn * KVBLK <= q0w + 31) {
        const char* kb = (const char*)&Klds[(t + 1) & 1][grp][0];
        __builtin_amdgcn_s_setprio(1);
#pragma unroll
        for (int kk = 0; kk < 8; ++kk) {
          bf16x8 ka = *(const bf16x8*)(kb + ((col * 256 + kk * 32 + hi * 16) ^ cswz));
          stn = mfma32(ka, qf[kk], stn);
        }
        __builtin_amdgcn_s_setprio(0);
      }

      // ---- stage next buffers (consume last iter's loads), issue new loads ----
      if (t + 2 < T) stageK(t + 2);
      if (t + 1 < T) stageV(t + 1);
      if (t + 3 < T) loadK(t + 3);
      if (t + 2 < T) loadV(t + 2);

      // ---- finish chunk t: mask, softmax, repack, PV ----
      const int kv0 = (4 * t + grp) * KVBLK;
      if (kv0 <= q0w + 31) {
        if (kv0 + KVBLK - 1 > q0w) {
          const int qk = q0w + col - kv0;
#pragma unroll
          for (int r = 0; r < 16; ++r) {
            const int krow = (r & 3) + 8 * (r >> 2) + 4 * hi;
            st_cur[r] = (krow <= qk) ? st_cur[r] : -1e30f;
          }
        }

        float t8[8];
#pragma unroll
        for (int r = 0; r < 8; ++r) t8[r] = fmaxf(st_cur[r], st_cur[r + 8]);
#pragma unroll
        for (int r = 0; r < 4; ++r) t8[r] = fmaxf(t8[r], t8[r + 4]);
        const float pmax = pair_max(fmaxf(fmaxf(t8[0], t8[1]), fmaxf(t8[2], t8[3])));

        if (!__all(pmax <= m + 11.0f)) {   // T13 defer-max
          const float mnew = fmaxf(m, pmax);
          const float al = __builtin_amdgcn_exp2f(m - mnew);
          m = mnew;
          l *= al;
#pragma unroll
          for (int r = 0; r < 16; ++r) {
            const int row = (r & 3) + 8 * (r >> 2) + 4 * hi;
            const float ar = lane_bcast(row, al);
            o0[r] *= ar; o1[r] *= ar; o2[r] *= ar; o3[r] *= ar;
          }
        }

        float s4[4] = {0.f, 0.f, 0.f, 0.f};
#pragma unroll
        for (int r = 0; r < 16; ++r) {
          st_cur[r] = __builtin_amdgcn_exp2f(st_cur[r] - m);
          s4[r & 3] += st_cur[r];
        }
        l += pair_sum((s4[0] + s4[1]) + (s4[2] + s4[3]));

        // P -> A-fragments (pack + 4 cross-half shuffles)
        unsigned cw[8];
#pragma unroll
        for (int i = 0; i < 8; ++i) cw[i] = pack2(st_cur[2 * i], st_cur[2 * i + 1]);
        const unsigned x1 = (unsigned)__shfl_xor((int)(hi ? cw[0] : cw[2]), 32);
        const unsigned x2 = (unsigned)__shfl_xor((int)(hi ? cw[1] : cw[3]), 32);
        const unsigned x3 = (unsigned)__shfl_xor((int)(hi ? cw[4] : cw[6]), 32);
        const unsigned x4 = (unsigned)__shfl_xor((int)(hi ? cw[5] : cw[7]), 32);
        union { unsigned u[4]; bf16x8 v; } pa0, pa1;
        pa0.u[0] = hi ? x1 : cw[0];  pa0.u[1] = hi ? x2 : cw[1];
        pa0.u[2] = hi ? cw[2] : x1;  pa0.u[3] = hi ? cw[3] : x2;
        pa1.u[0] = hi ? x3 : cw[4];  pa1.u[1] = hi ? x4 : cw[5];
        pa1.u[2] = hi ? cw[6] : x3;  pa1.u[3] = hi ? cw[7] : x4;

        const char* vb = (const char*)&Vt[t & 1][grp][0];
        __builtin_amdgcn_s_setprio(1);
#pragma unroll
        for (int ks = 0; ks < 2; ++ks) {
          const bf16x8 pa = ks ? pa1.v : pa0.v;
#define PV_STEP(ovar, dt) { \
          bf16x8 vf = *(const bf16x8*)(vb + ((((dt)*32 + col) * 64 + ks * 32 + hi * 16) ^ vswz)); \
          ovar = mfma32(pa, vf, ovar); }
          PV_STEP(o0, 0) PV_STEP(o1, 1) PV_STEP(o2, 2) PV_STEP(o3, 3)
#undef PV_STEP
        }
        __builtin_amdgcn_s_setprio(0);
      }
      pipeline_barrier();
      st_cur = stn;
    }

    // ---- merge 4 key-group partials: (1->0, 3->2) in parallel, then (2->0) ----
    float* ob  = reinterpret_cast<float*>(&Klds[0][0][0]); // 16384 floats: region r at r*8192
    float* mlb = reinterpret_cast<float*>(&Vt[0][0][0]);   // region r at r*512
    float f0 = 1.f, f1 = 0.f;
    {
      const int src  = grp & 1;               // groups 1,3 are sources
      float* obr = ob  + (grp >> 1) * 8192;
      float* mlr = mlb + (grp >> 1) * 512;
      if (src) {
        mlr[wq * 128 + lane] = m;
        mlr[wq * 128 + 64 + lane] = l;
#pragma unroll
        for (int r = 0; r < 16; ++r) {
          obr[wq * 1024 + r * 64 + lane] = o0[r];
          obr[4096 + wq * 1024 + r * 64 + lane] = o1[r];
        }
      }
      __syncthreads();
      if (!src) {
        const float m1 = mlr[wq * 128 + lane];
        const float l1 = mlr[wq * 128 + 64 + lane];
        const float mS = fmaxf(m, m1);
        f0 = __builtin_amdgcn_exp2f(m - mS);
        f1 = __builtin_amdgcn_exp2f(m1 - mS);
        m = mS;
        l = l * f0 + l1 * f1;
#pragma unroll
        for (int r = 0; r < 16; ++r) {
          const int row = (r & 3) + 8 * (r >> 2) + 4 * hi;
          const float a0 = lane_bcast(row, f0), a1 = lane_bcast(row, f1);
          o0[r] = o0[r] * a0 + obr[wq * 1024 + r * 64 + lane] * a1;
          o1[r] = o1[r] * a0 + obr[4096 + wq * 1024 + r * 64 + lane] * a1;
        }
      }
      __syncthreads();
      if (src) {
#pragma unroll
        for (int r = 0; r < 16; ++r) {
          obr[wq * 1024 + r * 64 + lane] = o2[r];
          obr[4096 + wq * 1024 + r * 64 + lane] = o3[r];
        }
      }
      __syncthreads();
      if (!src) {
#pragma unroll
        for (int r = 0; r < 16; ++r) {
          const int row = (r & 3) + 8 * (r >> 2) + 4 * hi;
          const float a0 = lane_bcast(row, f0), a1 = lane_bcast(row, f1);
          o2[r] = o2[r] * a0 + obr[wq * 1024 + r * 64 + lane] * a1;
          o3[r] = o3[r] * a0 + obr[4096 + wq * 1024 + r * 64 + lane] * a1;
        }
      }
      __syncthreads();
    }
    {
      if (grp == 2) {
        mlb[wq * 128 + lane] = m;
        mlb[wq * 128 + 64 + lane] = l;
#pragma unroll
        for (int r = 0; r < 16; ++r) {
          ob[wq * 1024 + r * 64 + lane] = o0[r];
          ob[4096 + wq * 1024 + r * 64 + lane] = o1[r];
        }
      }
      __syncthreads();
      if (grp == 0) {
        const float m1 = mlb[wq * 128 + lane];
        const float l1 = mlb[wq * 128 + 64 + lane];
        const float mS = fmaxf(m, m1);
        f0 = __builtin_amdgcn_exp2f(m - mS);
        f1 = __builtin_amdgcn_exp2f(m1 - mS);
        l = l * f0 + l1 * f1;
#pragma unroll
        for (int r = 0; r < 16; ++r) {
          const int row = (r & 3) + 8 * (r >> 2) + 4 * hi;
          const float a0 = lane_bcast(row, f0), a1 = lane_bcast(row, f1);
          o0[r] = o0[r] * a0 + ob[wq * 1024 + r * 64 + lane] * a1;
          o1[r] = o1[r] * a0 + ob[4096 + wq * 1024 + r * 64 + lane] * a1;
        }
      }
      __syncthreads();
      if (grp == 2) {
#pragma unroll
        for (int r = 0; r < 16; ++r) {
          ob[wq * 1024 + r * 64 + lane] = o2[r];
          ob[4096 + wq * 1024 + r * 64 + lane] = o3[r];
        }
      }
      __syncthreads();
      if (grp == 0) {
#pragma unroll
        for (int r = 0; r < 16; ++r) {
          const int row = (r & 3) + 8 * (r >> 2) + 4 * hi;
          const float a0 = lane_bcast(row, f0), a1 = lane_bcast(row, f1);
          o2[r] = o2[r] * a0 + ob[wq * 1024 + r * 64 + lane] * a1;
          o3[r] = o3[r] * a0 + ob[4096 + wq * 1024 + r * 64 + lane] * a1;
        }
        // ---- epilogue: store ----
        const float linv = 1.0f / l;
#pragma unroll
        for (int r = 0; r < 16; ++r) {
          const int row = (r & 3) + 8 * (r >> 2) + 4 * hi;
          const float lr = lane_bcast(row, linv);
          float* op = O + base + (size_t)(q0w + row) * RS + col;
          op[0]  = o0[r] * lr;
          op[32] = o1[r] * lr;
          op[64] = o2[r] * lr;
          op[96] = o3[r] * lr;
        }
      }
    }
    __syncthreads();   // protect merge scratch before next tile's staging
  }
}

} // namespace

extern "C" void kernel_launch(void* const* d_in, const int* /*in_sizes*/, int /*n_in*/,
                              void* d_out, int /*out_size*/, void* /*d_ws*/, size_t /*ws_size*/,
                              hipStream_t stream) {
  const float* q = (const float*)d_in[0];
  const float* k = (const float*)d_in[1];
  const float* v = (const float*)d_in[2];
  float* o = (float*)d_out;
  dim3 grid(256);    // 1 block/CU (128 KB LDS), all blocks = 17 supersteps
  dim3 blk(1024);
  hipLaunchKernelGGL(fa_fwd, grid, blk, 0, stream, q, k, v, o);
}